// Round 7
// baseline (566.044 us; speedup 1.0000x reference)
//
#include <hip/hip_runtime.h>
#include <hip/hip_bf16.h>
#include <hip/hip_fp16.h>
#include <math.h>

// Problem constants (from reference)
#define NN 50000
#define EE 1600000
#define NFEAT 256
#define NHID 128
#define RNG 12500  // NN/4 — fill pass range (ci window 1.6MB < 4MB L2/XCD)
#define NPASS 4
#define CPAD 16    // counter padding: one counter per 64B line

typedef _Float16 f16;
typedef _Float16 f16x8 __attribute__((ext_vector_type(8)));
typedef float f32x4 __attribute__((ext_vector_type(4)));

// ---------------------------------------------------------------------------
// Combined prep: fp32->fp16 convert of x, zero padded counters, convert+
// transpose all weights. One dispatch, block ranges keep each part coalesced.
struct WPtrs {
    const float* s[10];
    f16* d[10];
};

__global__ __launch_bounds__(256) void k_prep(const float* __restrict__ x,
                                              f16* __restrict__ xh, int n4,
                                              int* __restrict__ cnt, int nz4,
                                              WPtrs wp, int wtotal,
                                              int zb0, int wb0, int wblocks) {
    int b = blockIdx.x;
    if (b < zb0) {
        int i = b * 256 + threadIdx.x;
        if (i < n4) {
            float4 v = reinterpret_cast<const float4*>(x)[i];
            f16 h0 = (f16)v.x, h1 = (f16)v.y, h2 = (f16)v.z, h3 = (f16)v.w;
            f16* d = xh + (size_t)i * 4;
            d[0] = h0; d[1] = h1; d[2] = h2; d[3] = h3;
        }
    } else if (b < wb0) {
        int i = (b - zb0) * 256 + threadIdx.x;
        if (i < nz4) reinterpret_cast<int4*>(cnt)[i] = make_int4(0, 0, 0, 0);
    } else {
        for (int idx = (b - wb0) * 256 + threadIdx.x; idx < wtotal;
             idx += wblocks * 256) {
            int wsel, rem, K;
            if (idx < 3 * 32768) { wsel = idx >> 15; rem = idx & 32767; K = 256; }
            else { int t = idx - 3 * 32768; wsel = 3 + (t >> 14); rem = t & 16383; K = 128; }
            int k = rem >> 7, c = rem & 127;
            wp.d[wsel][c * K + k] = (f16)wp.s[wsel][rem];
        }
    }
}

// slot-record pass: epack[e] = (slot<<16) | row. Slot is position within the
// destination bucket (atomic-rate-wall limited, ~25G atomics/s measured —
// padding beyond CPAD gave only 9%, so count is the binding constraint).
// Max degree of this fixed random graph is ~70 << 32768, so packing is safe.
__global__ void k_slot(const int* __restrict__ row, int* __restrict__ cnt,
                       int* __restrict__ epack, int e) {
    int i = blockIdx.x * 256 + threadIdx.x;
    if (i < e) {
        int r = row[i];
        int s = atomicAdd(&cnt[(size_t)r * CPAD], 1);
        epack[i] = (s << 16) | r;
    }
}

// scan step 1: per-block (256-elem) sums of padded counters
__global__ void k_scan1(const int* __restrict__ cnt, int* __restrict__ bsum, int n) {
    __shared__ int s[256];
    int t = threadIdx.x;
    int i = blockIdx.x * 256 + t;
    s[t] = (i < n) ? cnt[(size_t)i * CPAD] : 0;
    __syncthreads();
    for (int off = 128; off > 0; off >>= 1) {
        if (t < off) s[t] += s[t + off];
        __syncthreads();
    }
    if (t == 0) bsum[blockIdx.x] = s[0];
}

// scan step 2+3 fused: each block scans the block sums itself (nb<=256),
// then does its 256-element exclusive scan -> rp, invd.
__global__ void k_scan3(const int* __restrict__ cnt, const int* __restrict__ bsum,
                        int* __restrict__ rp, float* __restrict__ invd,
                        int n, int nb) {
    __shared__ int buf[2][256];
    __shared__ int bpre[2][256];
    int t = threadIdx.x;

    bpre[0][t] = (t < nb) ? bsum[t] : 0;
    __syncthreads();
    int bs = 0;
    for (int off = 1; off < 256; off <<= 1) {
        int v = bpre[bs][t];
        if (t >= off) v += bpre[bs][t - off];
        bpre[bs ^ 1][t] = v;
        bs ^= 1;
        __syncthreads();
    }
    int base = (blockIdx.x == 0) ? 0 : bpre[bs][blockIdx.x - 1];

    int i = blockIdx.x * 256 + t;
    int v = (i < n) ? cnt[(size_t)i * CPAD] : 0;
    buf[0][t] = v;
    __syncthreads();
    int sel = 0;
    for (int off = 1; off < 256; off <<= 1) {
        int x = buf[sel][t];
        if (t >= off) x += buf[sel][t - off];
        buf[sel ^ 1][t] = x;
        sel ^= 1;
        __syncthreads();
    }
    int incl = buf[sel][t];
    int excl = incl - v;
    if (i < n) {
        rp[i] = base + excl;
        invd[i] = 1.0f / fmaxf((float)v, 1.0f);
        if (i == n - 1) rp[n] = base + incl;  // == E
    }
}

// range-partitioned fill, no atomics (live ci window L2-resident). Reads only
// epack+col per pass (slot packed with row -> no separate eslot array).
__global__ void k_fill(const int* __restrict__ epack, const int* __restrict__ col,
                       const int* __restrict__ rp, int* __restrict__ ci, int e) {
    int i = blockIdx.x * 256 + threadIdx.x;
    if (i >= e) return;
    int pk = epack[i];
    int r = pk & 0xFFFF;
    int lo = blockIdx.y * RNG;
    if (r >= lo && r < lo + RNG) ci[rp[r] + (pk >> 16)] = col[i];
}

// ---------------------------------------------------------------------------
// Fused SAGE aggregation (fp16 features, d=128):
//   OUT[node] = T[node] + invd[node] * sum_{nbr} P[nbr]
// 16 lanes per node, 16B per lane, 8-deep unrolled gather, fp32 accum.
__global__ __launch_bounds__(256) void k_agg2h(const f16* __restrict__ P,
                                               const int* __restrict__ rp,
                                               const int* __restrict__ ci,
                                               const float* __restrict__ invd,
                                               const f16* __restrict__ T,
                                               f16* __restrict__ OUT, int n) {
    int node = blockIdx.x * 16 + (threadIdx.x >> 4);
    if (node >= n) return;
    int lane = threadIdx.x & 15;
    int s = rp[node], e = rp[node + 1];
    float acc[8];
#pragma unroll
    for (int q = 0; q < 8; ++q) acc[q] = 0.0f;
    int j = s;
    for (; j + 8 <= e; j += 8) {
        f16x8 v[8];
#pragma unroll
        for (int u = 0; u < 8; ++u)
            v[u] = *reinterpret_cast<const f16x8*>(P + (size_t)ci[j + u] * 128 + lane * 8);
#pragma unroll
        for (int q = 0; q < 8; ++q)
            acc[q] += (((float)v[0][q] + (float)v[1][q]) + ((float)v[2][q] + (float)v[3][q])) +
                      (((float)v[4][q] + (float)v[5][q]) + ((float)v[6][q] + (float)v[7][q]));
    }
    for (; j < e; ++j) {
        f16x8 v0 = *reinterpret_cast<const f16x8*>(P + (size_t)ci[j] * 128 + lane * 8);
#pragma unroll
        for (int q = 0; q < 8; ++q) acc[q] += (float)v0[q];
    }
    float scl = invd[node];
    f16x8 tv = *reinterpret_cast<const f16x8*>(T + (size_t)node * 128 + lane * 8);
    f16x8 o;
#pragma unroll
    for (int q = 0; q < 8; ++q) o[q] = (f16)((float)tv[q] + scl * acc[q]);
    *reinterpret_cast<f16x8*>(OUT + (size_t)node * 128 + lane * 8) = o;
}

// ---------------------------------------------------------------------------
// Pipelined MFMA fp16 GEMM.
// Tile: BM=128, BN=128, BK=32; 256 threads = 4 waves (2x2), wave tile 64x64
// (16 MFMA / ktile / wave, 8 ds_read_b128 / ktile / wave).
// Double-buffered LDS, reg-staged global prefetch, ONE barrier per ktile.
// LDS: 2 buf x (A+B) x 128 x 40 halves = 40KB -> 3 blocks/CU.
#define LDSSTR 40
#define LBUF (128 * LDSSTR)

struct Stage { uint4 a[2], b[2]; };

__device__ __forceinline__ void ld_tile(Stage& s, const f16* __restrict__ A,
                                        const f16* __restrict__ Wt, int row0,
                                        int K, int kb, int tid, int n) {
#pragma unroll
    for (int i = 0; i < 2; ++i) {
        int idx = tid + i * 256;          // 0..511
        int r = idx >> 2, ch = idx & 3;   // row, 16B-chunk
        int gr = row0 + r;
        s.a[i] = (gr < n)
            ? *reinterpret_cast<const uint4*>(A + (size_t)gr * K + kb + ch * 8)
            : make_uint4(0, 0, 0, 0);
        s.b[i] = *reinterpret_cast<const uint4*>(Wt + (size_t)r * K + kb + ch * 8);
    }
}

__device__ __forceinline__ void st_tile(const Stage& s, f16* __restrict__ sA,
                                        f16* __restrict__ sB, int tid) {
#pragma unroll
    for (int i = 0; i < 2; ++i) {
        int idx = tid + i * 256;
        int r = idx >> 2, ch = idx & 3;
        *reinterpret_cast<uint4*>(sA + r * LDSSTR + ch * 8) = s.a[i];
        *reinterpret_cast<uint4*>(sB + r * LDSSTR + ch * 8) = s.b[i];
    }
}

__device__ __forceinline__ void mfma_tile(const f16* __restrict__ sA,
                                          const f16* __restrict__ sB,
                                          f32x4 acc[4][4], int wr, int wc,
                                          int lr, int lk) {
    f16x8 aF[4], bF[4];
#pragma unroll
    for (int m = 0; m < 4; ++m)
        aF[m] = *reinterpret_cast<const f16x8*>(sA + (wr * 64 + m * 16 + lr) * LDSSTR + lk);
#pragma unroll
    for (int q = 0; q < 4; ++q)
        bF[q] = *reinterpret_cast<const f16x8*>(sB + (wc * 64 + q * 16 + lr) * LDSSTR + lk);
#pragma unroll
    for (int m = 0; m < 4; ++m)
#pragma unroll
        for (int q = 0; q < 4; ++q)
            acc[m][q] = __builtin_amdgcn_mfma_f32_16x16x32_f16(aF[m], bF[q],
                                                               acc[m][q], 0, 0, 0);
}

// Multi-output MFMA GEMM: A [n x K] fp16, blockIdx.y selects (W,bias,C).
template <int K, int NW, bool F32OUT>
__global__ __launch_bounds__(256, 3) void k_mgemm(const f16* __restrict__ A,
                                                  const f16* __restrict__ Wt0,
                                                  const f16* __restrict__ Wt1,
                                                  const f16* __restrict__ Wt2,
                                                  const float* __restrict__ bias0,
                                                  void* __restrict__ C0,
                                                  void* __restrict__ C1,
                                                  void* __restrict__ C2, int n) {
    constexpr int NT = K / 32;
    __shared__ f16 lds[2][2 * LBUF];

    const f16* Wt = Wt0;
    const float* bias = bias0;
    void* C = C0;
    if (NW > 1 && blockIdx.y == 1) { Wt = Wt1; bias = nullptr; C = C1; }
    if (NW > 2 && blockIdx.y == 2) { Wt = Wt2; bias = nullptr; C = C2; }

    const int tid = threadIdx.x;
    const int row0 = blockIdx.x * 128;
    const int wid = tid >> 6, l = tid & 63;
    const int wr = wid >> 1, wc = wid & 1;
    const int lr = l & 15, lk = (l >> 4) * 8;

    f32x4 acc[4][4];
#pragma unroll
    for (int m = 0; m < 4; ++m)
#pragma unroll
        for (int q = 0; q < 4; ++q) acc[m][q] = (f32x4){0.f, 0.f, 0.f, 0.f};

    Stage s;
    ld_tile(s, A, Wt, row0, K, 0, tid, n);
    st_tile(s, lds[0], lds[0] + LBUF, tid);
    __syncthreads();

    int cur = 0;
    for (int t = 0; t < NT; ++t) {
        Stage nx;
        if (t + 1 < NT) ld_tile(nx, A, Wt, row0, K, (t + 1) * 32, tid, n);
        mfma_tile(lds[cur], lds[cur] + LBUF, acc, wr, wc, lr, lk);
        if (t + 1 < NT) {
            st_tile(nx, lds[cur ^ 1], lds[cur ^ 1] + LBUF, tid);
            __syncthreads();
            cur ^= 1;
        }
    }

    const int lr4 = (l >> 4) * 4;
#pragma unroll
    for (int m = 0; m < 4; ++m)
#pragma unroll
        for (int q = 0; q < 4; ++q) {
            int c = wc * 64 + q * 16 + (l & 15);
            float b = bias ? bias[c] : 0.0f;
#pragma unroll
            for (int reg = 0; reg < 4; ++reg) {
                int r = row0 + wr * 64 + m * 16 + lr4 + reg;
                if (r >= n) continue;
                float v = acc[m][q][reg] + b;
                if (F32OUT) ((float*)C)[(size_t)r * 128 + c] = v;
                else        ((f16*)C)[(size_t)r * 128 + c] = (f16)v;
            }
        }
}

// Gated-skip MFMA GEMM: G = sc@Wci + t0@Wco; z=sigmoid(G+bci+bco);
// out = z*t0 + (1-z)*sc, optional relu, fp16 out.
template <int RELU>
__global__ __launch_bounds__(256, 3) void k_ggemm(const f16* __restrict__ Asc,
                                                  const f16* __restrict__ At0,
                                                  const f16* __restrict__ Wci,
                                                  const f16* __restrict__ Wco,
                                                  const float* __restrict__ bci,
                                                  const float* __restrict__ bco,
                                                  f16* __restrict__ C, int n) {
    constexpr int NT = 8;  // 4 ktiles of sc@Wci + 4 of t0@Wco
    __shared__ f16 lds[2][2 * LBUF];

    const int tid = threadIdx.x;
    const int row0 = blockIdx.x * 128;
    const int wid = tid >> 6, l = tid & 63;
    const int wr = wid >> 1, wc = wid & 1;
    const int lr = l & 15, lk = (l >> 4) * 8;

    f32x4 acc[4][4];
#pragma unroll
    for (int m = 0; m < 4; ++m)
#pragma unroll
        for (int q = 0; q < 4; ++q) acc[m][q] = (f32x4){0.f, 0.f, 0.f, 0.f};

    Stage s;
    ld_tile(s, Asc, Wci, row0, 128, 0, tid, n);
    st_tile(s, lds[0], lds[0] + LBUF, tid);
    __syncthreads();

    int cur = 0;
    for (int t = 0; t < NT; ++t) {
        Stage nx;
        if (t + 1 < NT) {
            int tn = t + 1;
            const f16* An = (tn < 4) ? Asc : At0;
            const f16* Wn = (tn < 4) ? Wci : Wco;
            ld_tile(nx, An, Wn, row0, 128, (tn & 3) * 32, tid, n);
        }
        mfma_tile(lds[cur], lds[cur] + LBUF, acc, wr, wc, lr, lk);
        if (t + 1 < NT) {
            st_tile(nx, lds[cur ^ 1], lds[cur ^ 1] + LBUF, tid);
            __syncthreads();
            cur ^= 1;
        }
    }

    const int lr4 = (l >> 4) * 4;
#pragma unroll
    for (int m = 0; m < 4; ++m)
#pragma unroll
        for (int q = 0; q < 4; ++q) {
            int c = wc * 64 + q * 16 + (l & 15);
            float b = bci[c] + bco[c];
#pragma unroll
            for (int reg = 0; reg < 4; ++reg) {
                int r = row0 + wr * 64 + m * 16 + lr4 + reg;
                if (r >= n) continue;
                float v = acc[m][q][reg] + b;
                float z = 1.0f / (1.0f + __expf(-v));
                float o = (float)At0[(size_t)r * 128 + c];
                float sv = (float)Asc[(size_t)r * 128 + c];
                float outv = z * o + (1.0f - z) * sv;
                if (RELU) outv = fmaxf(outv, 0.0f);
                C[(size_t)r * 128 + c] = (f16)outv;
            }
        }
}

// ---------------------------------------------------------------------------
extern "C" void kernel_launch(void* const* d_in, const int* in_sizes, int n_in,
                              void* d_out, int out_size, void* d_ws, size_t ws_size,
                              hipStream_t stream) {
    const float* x    = (const float*)d_in[0];
    const int*   row  = (const int*)d_in[1];
    const int*   col  = (const int*)d_in[2];
    const float* W_sc = (const float*)d_in[3];
    const float* W_ci = (const float*)d_in[4];
    const float* b_ci = (const float*)d_in[5];
    const float* W_co = (const float*)d_in[6];
    const float* b_co = (const float*)d_in[7];
    const float* W0   = (const float*)d_in[8];
    const float* b0   = (const float*)d_in[9];
    const float* W1   = (const float*)d_in[10];
    const float* b1   = (const float*)d_in[11];
    const float* W2   = (const float*)d_in[12];
    const float* b2   = (const float*)d_in[13];
    const float* Wf   = (const float*)d_in[14];
    const float* bf   = (const float*)d_in[15];
    float* out = (float*)d_out;

    char* p = (char*)d_ws;
    auto alloc = [&](size_t bytes) {
        char* q = p;
        p += (bytes + 255) & ~(size_t)255;
        return q;
    };
    int*   cnt   = (int*)alloc((size_t)NN * CPAD * 4);  // padded: 1 counter / 64B
    int*   rp    = (int*)alloc((NN + 1) * 4);
    int*   bsum  = (int*)alloc(256 * 4);
    float* invd  = (float*)alloc(NN * 4);
    int*   ci    = (int*)alloc(EE * 4);
    int*   epack = (int*)alloc(EE * 4);
    f16*   x_h   = (f16*)alloc((size_t)NN * 256 * 2);
    f16*   sc_h  = (f16*)alloc((size_t)NN * 128 * 2);
    f16*   T_h   = (f16*)alloc((size_t)NN * 128 * 2);
    f16*   P_h   = (f16*)alloc((size_t)NN * 128 * 2);
    f16*   t0_h  = (f16*)alloc((size_t)NN * 128 * 2);
    f16*   t1_h  = (f16*)alloc((size_t)NN * 128 * 2);
    // transposed fp16 weights [128 x K]
    f16* W0t_t = (f16*)alloc(256 * 128 * 2);
    f16* W0b_t = (f16*)alloc(256 * 128 * 2);
    f16* Wsc_t = (f16*)alloc(256 * 128 * 2);
    f16* W1t_t = (f16*)alloc(128 * 128 * 2);
    f16* W1b_t = (f16*)alloc(128 * 128 * 2);
    f16* W2t_t = (f16*)alloc(128 * 128 * 2);
    f16* W2b_t = (f16*)alloc(128 * 128 * 2);
    f16* Wci_t = (f16*)alloc(128 * 128 * 2);
    f16* Wco_t = (f16*)alloc(128 * 128 * 2);
    f16* Wf_t  = (f16*)alloc(128 * 128 * 2);

    const int NB_N  = (NN + 255) / 256;   // 196
    const int NB_E  = (EE + 255) / 256;   // 6250
    const int GB    = (NN + 127) / 128;   // 391 mfma-gemm row-blocks
    const int AGG_B = (NN + 15) / 16;     // 3125 blocks (16 nodes/block)

    // ---- prep: convert x, zero counters, convert+transpose weights ----
    const int N4   = NN * 256 / 4;               // 3,200,000 float4
    const int NZ4  = NN * CPAD / 4;              // 200,000 int4
    const int ZB0  = (N4 + 255) / 256;           // 12500
    const int WB0  = ZB0 + (NZ4 + 255) / 256;    // +782
    const int WBLK = 84;
    const int WTOT = 3 * 32768 + 7 * 16384;      // 212,992
    WPtrs wp;
    wp.s[0] = W0;             wp.d[0] = W0t_t;
    wp.s[1] = W0 + 256 * 128; wp.d[1] = W0b_t;
    wp.s[2] = W_sc;           wp.d[2] = Wsc_t;
    wp.s[3] = W1;             wp.d[3] = W1t_t;
    wp.s[4] = W1 + 128 * 128; wp.d[4] = W1b_t;
    wp.s[5] = W2;             wp.d[5] = W2t_t;
    wp.s[6] = W2 + 128 * 128; wp.d[6] = W2b_t;
    wp.s[7] = W_ci;           wp.d[7] = Wci_t;
    wp.s[8] = W_co;           wp.d[8] = Wco_t;
    wp.s[9] = Wf;             wp.d[9] = Wf_t;
    k_prep<<<WB0 + WBLK, 256, 0, stream>>>(x, x_h, N4, cnt, NZ4, wp, WTOT,
                                           ZB0, WB0, WBLK);

    // ---- graph structure ----
    k_slot<<<NB_E, 256, 0, stream>>>(row, cnt, epack, EE);
    k_scan1<<<NB_N, 256, 0, stream>>>(cnt, bsum, NN);
    k_scan3<<<NB_N, 256, 0, stream>>>(cnt, bsum, rp, invd, NN, NB_N);
    k_fill<<<dim3(NB_E, NPASS), 256, 0, stream>>>(epack, col, rp, ci, EE);

    // ---- layer 0:  T = x@W0top + b0, P = x@W0bot, sc = x@W_sc ----
    k_mgemm<256, 3, false><<<dim3(GB, 3), 256, 0, stream>>>(
        x_h, W0t_t, W0b_t, Wsc_t, b0, T_h, P_h, sc_h, NN);
    k_agg2h<<<AGG_B, 256, 0, stream>>>(P_h, rp, ci, invd, T_h, t0_h, NN);    // o1
    k_ggemm<1><<<GB, 256, 0, stream>>>(sc_h, t0_h, Wci_t, Wco_t,
                                       b_ci, b_co, t1_h, NN);                // o3

    // ---- layer 1 ----
    k_mgemm<128, 2, false><<<dim3(GB, 2), 256, 0, stream>>>(
        t1_h, W1t_t, W1b_t, nullptr, b1, T_h, P_h, nullptr, NN);
    k_agg2h<<<AGG_B, 256, 0, stream>>>(P_h, rp, ci, invd, T_h, t0_h, NN);    // o4
    k_ggemm<1><<<GB, 256, 0, stream>>>(sc_h, t0_h, Wci_t, Wco_t,
                                       b_ci, b_co, t1_h, NN);                // o6

    // ---- layer 2 ----
    k_mgemm<128, 2, false><<<dim3(GB, 2), 256, 0, stream>>>(
        t1_h, W2t_t, W2b_t, nullptr, b2, T_h, P_h, nullptr, NN);
    k_agg2h<<<AGG_B, 256, 0, stream>>>(P_h, rp, ci, invd, T_h, t0_h, NN);    // o7
    k_ggemm<0><<<GB, 256, 0, stream>>>(sc_h, t0_h, Wci_t, Wco_t,
                                       b_ci, b_co, t1_h, NN);                // o8

    // ---- classifier: out = t1 @ Wf + bf (fp32 out) ----
    k_mgemm<128, 1, true><<<GB, 256, 0, stream>>>(
        t1_h, Wf_t, nullptr, nullptr, bf, out, nullptr, nullptr, NN);
}

// Round 10
// 544.667 us; speedup vs baseline: 1.0392x; 1.0392x over previous
//
#include <hip/hip_runtime.h>
#include <hip/hip_bf16.h>
#include <hip/hip_fp16.h>
#include <math.h>

// Problem constants (from reference)
#define NN 50000
#define EE 1600000
#define NFEAT 256
#define NHID 128
#define RNG 12500  // NN/4 — fill pass range (ci window 1.6MB < 4MB L2/XCD)
#define NPASS 4
#define CPAD 16    // counter padding: one counter per 64B line

typedef _Float16 f16;
typedef _Float16 f16x8 __attribute__((ext_vector_type(8)));
typedef _Float16 f16x4 __attribute__((ext_vector_type(4)));
typedef float f32x4 __attribute__((ext_vector_type(4)));

// ---------------------------------------------------------------------------
// Combined prep: fp32->fp16 convert of x, zero padded counters, convert+
// transpose all weights. One dispatch, block ranges keep each part coalesced.
struct WPtrs {
    const float* s[10];
    f16* d[10];
};

__global__ __launch_bounds__(256) void k_prep(const float* __restrict__ x,
                                              f16* __restrict__ xh, int n4,
                                              int* __restrict__ cnt, int nz4,
                                              WPtrs wp, int wtotal,
                                              int zb0, int wb0, int wblocks) {
    int b = blockIdx.x;
    if (b < zb0) {
        int i = b * 256 + threadIdx.x;
        if (i < n4) {
            float4 v = reinterpret_cast<const float4*>(x)[i];
            f16x4 h = {(f16)v.x, (f16)v.y, (f16)v.z, (f16)v.w};
            reinterpret_cast<f16x4*>(xh)[i] = h;
        }
    } else if (b < wb0) {
        int i = (b - zb0) * 256 + threadIdx.x;
        if (i < nz4) reinterpret_cast<int4*>(cnt)[i] = make_int4(0, 0, 0, 0);
    } else {
        for (int idx = (b - wb0) * 256 + threadIdx.x; idx < wtotal;
             idx += wblocks * 256) {
            int wsel, rem, K;
            if (idx < 3 * 32768) { wsel = idx >> 15; rem = idx & 32767; K = 256; }
            else { int t = idx - 3 * 32768; wsel = 3 + (t >> 14); rem = t & 16383; K = 128; }
            int k = rem >> 7, c = rem & 127;
            wp.d[wsel][c * K + k] = (f16)wp.s[wsel][rem];
        }
    }
}

// slot-record pass: epack[e] = (slot<<16) | row. Atomic-rate-wall limited
// (~25G atomics/s; CPAD padding beyond this gave only 9% — parked).
__global__ void k_slot(const int* __restrict__ row, int* __restrict__ cnt,
                       int* __restrict__ epack, int e) {
    int i = blockIdx.x * 256 + threadIdx.x;
    if (i < e) {
        int r = row[i];
        int s = atomicAdd(&cnt[(size_t)r * CPAD], 1);
        epack[i] = (s << 16) | r;
    }
}

// scan step 1: per-block (256-elem) sums of padded counters
__global__ void k_scan1(const int* __restrict__ cnt, int* __restrict__ bsum, int n) {
    __shared__ int s[256];
    int t = threadIdx.x;
    int i = blockIdx.x * 256 + t;
    s[t] = (i < n) ? cnt[(size_t)i * CPAD] : 0;
    __syncthreads();
    for (int off = 128; off > 0; off >>= 1) {
        if (t < off) s[t] += s[t + off];
        __syncthreads();
    }
    if (t == 0) bsum[blockIdx.x] = s[0];
}

// scan step 2+3 fused: each block scans the block sums itself (nb<=256),
// then does its 256-element exclusive scan -> rp, invd.
__global__ void k_scan3(const int* __restrict__ cnt, const int* __restrict__ bsum,
                        int* __restrict__ rp, float* __restrict__ invd,
                        int n, int nb) {
    __shared__ int buf[2][256];
    __shared__ int bpre[2][256];
    int t = threadIdx.x;

    bpre[0][t] = (t < nb) ? bsum[t] : 0;
    __syncthreads();
    int bs = 0;
    for (int off = 1; off < 256; off <<= 1) {
        int v = bpre[bs][t];
        if (t >= off) v += bpre[bs][t - off];
        bpre[bs ^ 1][t] = v;
        bs ^= 1;
        __syncthreads();
    }
    int base = (blockIdx.x == 0) ? 0 : bpre[bs][blockIdx.x - 1];

    int i = blockIdx.x * 256 + t;
    int v = (i < n) ? cnt[(size_t)i * CPAD] : 0;
    buf[0][t] = v;
    __syncthreads();
    int sel = 0;
    for (int off = 1; off < 256; off <<= 1) {
        int x = buf[sel][t];
        if (t >= off) x += buf[sel][t - off];
        buf[sel ^ 1][t] = x;
        sel ^= 1;
        __syncthreads();
    }
    int incl = buf[sel][t];
    int excl = incl - v;
    if (i < n) {
        rp[i] = base + excl;
        invd[i] = 1.0f / fmaxf((float)v, 1.0f);
        if (i == n - 1) rp[n] = base + incl;  // == E
    }
}

// range-partitioned fill, no atomics (live ci window L2-resident).
__global__ void k_fill(const int* __restrict__ epack, const int* __restrict__ col,
                       const int* __restrict__ rp, int* __restrict__ ci, int e) {
    int i = blockIdx.x * 256 + threadIdx.x;
    if (i >= e) return;
    int pk = epack[i];
    int r = pk & 0xFFFF;
    int lo = blockIdx.y * RNG;
    if (r >= lo && r < lo + RNG) ci[rp[r] + (pk >> 16)] = col[i];
}

// ---------------------------------------------------------------------------
// Fused SAGE aggregation (fp16 features, d=128):
//   OUT[node] = T[node] + invd[node] * sum_{nbr} P[nbr]
// 16 lanes per node, 16B per lane, 8-deep unrolled gather, fp32 accum.
__global__ __launch_bounds__(256) void k_agg2h(const f16* __restrict__ P,
                                               const int* __restrict__ rp,
                                               const int* __restrict__ ci,
                                               const float* __restrict__ invd,
                                               const f16* __restrict__ T,
                                               f16* __restrict__ OUT, int n) {
    int node = blockIdx.x * 16 + (threadIdx.x >> 4);
    if (node >= n) return;
    int lane = threadIdx.x & 15;
    int s = rp[node], e = rp[node + 1];
    float acc[8];
#pragma unroll
    for (int q = 0; q < 8; ++q) acc[q] = 0.0f;
    int j = s;
    for (; j + 8 <= e; j += 8) {
        f16x8 v[8];
#pragma unroll
        for (int u = 0; u < 8; ++u)
            v[u] = *reinterpret_cast<const f16x8*>(P + (size_t)ci[j + u] * 128 + lane * 8);
#pragma unroll
        for (int q = 0; q < 8; ++q)
            acc[q] += (((float)v[0][q] + (float)v[1][q]) + ((float)v[2][q] + (float)v[3][q])) +
                      (((float)v[4][q] + (float)v[5][q]) + ((float)v[6][q] + (float)v[7][q]));
    }
    for (; j < e; ++j) {
        f16x8 v0 = *reinterpret_cast<const f16x8*>(P + (size_t)ci[j] * 128 + lane * 8);
#pragma unroll
        for (int q = 0; q < 8; ++q) acc[q] += (float)v0[q];
    }
    float scl = invd[node];
    f16x8 tv = *reinterpret_cast<const f16x8*>(T + (size_t)node * 128 + lane * 8);
    f16x8 o;
#pragma unroll
    for (int q = 0; q < 8; ++q) o[q] = (f16)((float)tv[q] + scl * acc[q]);
    *reinterpret_cast<f16x8*>(OUT + (size_t)node * 128 + lane * 8) = o;
}

// ---------------------------------------------------------------------------
// MFMA GEMM common: BM=64, BN=128, BK=32; 256 threads = 4 waves (2x2),
// wave tile 32x64. Fragment layout (gfx950 16x16x32 f16):
// A: row=lane&15, k=(lane>>4)*8+j ; B: col=lane&15, same k;
// C/D: col=lane&15, row=(lane>>4)*4+reg.
#define LDSSTR 40

__device__ __forceinline__ void stage_A(const f16* __restrict__ A, f16* sA,
                                        int row0, int K, int kb, int tid, int n) {
    int r = tid >> 2, ch = tid & 3;
    int gr = row0 + r;
    uint4 v = make_uint4(0, 0, 0, 0);
    if (gr < n) v = *reinterpret_cast<const uint4*>(A + (size_t)gr * K + kb + ch * 8);
    *reinterpret_cast<uint4*>(sA + r * LDSSTR + ch * 8) = v;
}

__device__ __forceinline__ void stage_B(const f16* __restrict__ Wt, f16* sB,
                                        int K, int kb, int tid) {
#pragma unroll
    for (int i = 0; i < 2; ++i) {
        int idx = tid + i * 256;
        int c = idx >> 2, ch = idx & 3;
        uint4 v = *reinterpret_cast<const uint4*>(Wt + (size_t)c * K + kb + ch * 8);
        *reinterpret_cast<uint4*>(sB + c * LDSSTR + ch * 8) = v;
    }
}

// Multi-output MFMA GEMM (layer 0): A [n x K] fp16, blockIdx.y selects
// (W,bias,C). Only y==0 applies bias0. (Known-good R5 structure.)
template <int K, int NW, bool F32OUT>
__global__ __launch_bounds__(256) void k_mgemm(const f16* __restrict__ A,
                                               const f16* __restrict__ Wt0,
                                               const f16* __restrict__ Wt1,
                                               const f16* __restrict__ Wt2,
                                               const float* __restrict__ bias0,
                                               void* __restrict__ C0,
                                               void* __restrict__ C1,
                                               void* __restrict__ C2, int n) {
    __shared__ f16 sA[64 * LDSSTR];
    __shared__ f16 sB[128 * LDSSTR];

    const f16* Wt = Wt0;
    const float* bias = bias0;
    void* C = C0;
    if (NW > 1 && blockIdx.y == 1) { Wt = Wt1; bias = nullptr; C = C1; }
    if (NW > 2 && blockIdx.y == 2) { Wt = Wt2; bias = nullptr; C = C2; }

    const int tid = threadIdx.x;
    const int row0 = blockIdx.x * 64;
    const int wid = tid >> 6, l = tid & 63;
    const int wr = wid >> 1, wc = wid & 1;
    const int lr = l & 15, lk = (l >> 4) * 8;

    f32x4 acc[2][4];
#pragma unroll
    for (int m = 0; m < 2; ++m)
#pragma unroll
        for (int q = 0; q < 4; ++q) acc[m][q] = (f32x4){0.f, 0.f, 0.f, 0.f};

    for (int kt = 0; kt < K / 32; ++kt) {
        stage_A(A, sA, row0, K, kt * 32, tid, n);
        stage_B(Wt, sB, K, kt * 32, tid);
        __syncthreads();
        f16x8 aF[2], bF[4];
#pragma unroll
        for (int m = 0; m < 2; ++m)
            aF[m] = *reinterpret_cast<f16x8*>(sA + (wr * 32 + m * 16 + lr) * LDSSTR + lk);
#pragma unroll
        for (int q = 0; q < 4; ++q)
            bF[q] = *reinterpret_cast<f16x8*>(sB + (wc * 64 + q * 16 + lr) * LDSSTR + lk);
#pragma unroll
        for (int m = 0; m < 2; ++m)
#pragma unroll
            for (int q = 0; q < 4; ++q)
                acc[m][q] = __builtin_amdgcn_mfma_f32_16x16x32_f16(aF[m], bF[q],
                                                                   acc[m][q], 0, 0, 0);
        __syncthreads();
    }

    const int lr4 = (l >> 4) * 4;
#pragma unroll
    for (int m = 0; m < 2; ++m)
#pragma unroll
        for (int q = 0; q < 4; ++q) {
            int c = wc * 64 + q * 16 + (l & 15);
            float b = bias ? bias[c] : 0.0f;
#pragma unroll
            for (int reg = 0; reg < 4; ++reg) {
                int r = row0 + wr * 32 + m * 16 + lr4 + reg;
                if (r >= n) continue;
                float v = acc[m][q][reg] + b;
                if (F32OUT) ((float*)C)[(size_t)r * 128 + c] = v;
                else        ((f16*)C)[(size_t)r * 128 + c] = (f16)v;
            }
        }
}

// ---------------------------------------------------------------------------
// Fused gated-skip + next-layer projections (row-local chain):
//   G  = sc@Wci + t0@Wco ; z = sigmoid(G + bci + bco)
//   t1 = z*t0 + (1-z)*sc  (relu if RELU)      [stays in LDS]
//   CLS=false: T = t1@WtT + bias2, P = t1@WtP   (fp16 out)
//   CLS=true : Fo = t1@WtT + bias2              (fp32 out, classifier)
// A-operands (sc,t0,t1) from LDS tiles [64][136] (2-way bank conflict = free);
// B-operands (weights) read directly from global (L2-resident, 128KB).
// 2 barriers per block total.
#define FSTR 136

template <int RELU, bool CLS>
__global__ __launch_bounds__(256) void k_fused(const f16* __restrict__ Asc,
                                               const f16* __restrict__ At0,
                                               const f16* __restrict__ Wci,
                                               const f16* __restrict__ Wco,
                                               const f16* __restrict__ WtT,
                                               const f16* __restrict__ WtP,
                                               const float* __restrict__ bci,
                                               const float* __restrict__ bco,
                                               const float* __restrict__ bias2,
                                               f16* __restrict__ To,
                                               f16* __restrict__ Po,
                                               float* __restrict__ Fo, int n) {
    __shared__ f16 lsc[64 * FSTR];
    __shared__ f16 lt0[64 * FSTR];
    __shared__ f16 lt1[64 * FSTR];

    const int tid = threadIdx.x;
    const int row0 = blockIdx.x * 64;
    const int wid = tid >> 6, l = tid & 63;
    const int wr = wid >> 1, wc = wid & 1;
    const int lr = l & 15, lk = (l >> 4) * 8;
    const int lr4 = (l >> 4) * 4;

    // stage sc,t0 tiles: 64 rows x 128 halves = 1024 uint4 per tile, 4/thread
#pragma unroll
    for (int i = 0; i < 4; ++i) {
        int idx = tid + i * 256;
        int r = idx >> 4, ch = idx & 15;
        int gr = row0 + r;
        uint4 vs = make_uint4(0, 0, 0, 0), vt = make_uint4(0, 0, 0, 0);
        if (gr < n) {
            vs = *reinterpret_cast<const uint4*>(Asc + (size_t)gr * 128 + ch * 8);
            vt = *reinterpret_cast<const uint4*>(At0 + (size_t)gr * 128 + ch * 8);
        }
        *reinterpret_cast<uint4*>(lsc + r * FSTR + ch * 8) = vs;
        *reinterpret_cast<uint4*>(lt0 + r * FSTR + ch * 8) = vt;
    }
    __syncthreads();

    // phase 1: G = sc@Wci + t0@Wco
    f32x4 accG[2][4];
#pragma unroll
    for (int m = 0; m < 2; ++m)
#pragma unroll
        for (int q = 0; q < 4; ++q) accG[m][q] = (f32x4){0.f, 0.f, 0.f, 0.f};

#pragma unroll
    for (int kt = 0; kt < 4; ++kt) {
        f16x8 aS[2], aT[2], bC[4], bO[4];
#pragma unroll
        for (int m = 0; m < 2; ++m) {
            int rr = (wr * 32 + m * 16 + lr) * FSTR + kt * 32 + lk;
            aS[m] = *reinterpret_cast<const f16x8*>(lsc + rr);
            aT[m] = *reinterpret_cast<const f16x8*>(lt0 + rr);
        }
#pragma unroll
        for (int q = 0; q < 4; ++q) {
            int c = wc * 64 + q * 16 + lr;
            bC[q] = *reinterpret_cast<const f16x8*>(Wci + (size_t)c * 128 + kt * 32 + lk);
            bO[q] = *reinterpret_cast<const f16x8*>(Wco + (size_t)c * 128 + kt * 32 + lk);
        }
#pragma unroll
        for (int m = 0; m < 2; ++m)
#pragma unroll
            for (int q = 0; q < 4; ++q) {
                accG[m][q] = __builtin_amdgcn_mfma_f32_16x16x32_f16(aS[m], bC[q],
                                                                    accG[m][q], 0, 0, 0);
                accG[m][q] = __builtin_amdgcn_mfma_f32_16x16x32_f16(aT[m], bO[q],
                                                                    accG[m][q], 0, 0, 0);
            }
    }

    // gating in C-layout; t1 -> LDS
#pragma unroll
    for (int m = 0; m < 2; ++m)
#pragma unroll
        for (int q = 0; q < 4; ++q) {
            int c = wc * 64 + q * 16 + (l & 15);
            float bb = bci[c] + bco[c];
#pragma unroll
            for (int reg = 0; reg < 4; ++reg) {
                int lrow = wr * 32 + m * 16 + lr4 + reg;
                float v = accG[m][q][reg] + bb;
                float z = 1.0f / (1.0f + __expf(-v));
                float o = (float)lt0[lrow * FSTR + c];
                float s = (float)lsc[lrow * FSTR + c];
                float t1v = z * o + (1.0f - z) * s;
                if (RELU) t1v = fmaxf(t1v, 0.0f);
                lt1[lrow * FSTR + c] = (f16)t1v;
            }
        }
    __syncthreads();

    // phase 2: T = t1@WtT (+bias2), P = t1@WtP
    f32x4 accT[2][4], accP[2][4];
#pragma unroll
    for (int m = 0; m < 2; ++m)
#pragma unroll
        for (int q = 0; q < 4; ++q) {
            accT[m][q] = (f32x4){0.f, 0.f, 0.f, 0.f};
            accP[m][q] = (f32x4){0.f, 0.f, 0.f, 0.f};
        }

#pragma unroll
    for (int kt = 0; kt < 4; ++kt) {
        f16x8 aF[2], bT[4], bP[4];
#pragma unroll
        for (int m = 0; m < 2; ++m)
            aF[m] = *reinterpret_cast<const f16x8*>(
                lt1 + (wr * 32 + m * 16 + lr) * FSTR + kt * 32 + lk);
#pragma unroll
        for (int q = 0; q < 4; ++q) {
            int c = wc * 64 + q * 16 + lr;
            bT[q] = *reinterpret_cast<const f16x8*>(WtT + (size_t)c * 128 + kt * 32 + lk);
            if (!CLS)
                bP[q] = *reinterpret_cast<const f16x8*>(WtP + (size_t)c * 128 + kt * 32 + lk);
        }
#pragma unroll
        for (int m = 0; m < 2; ++m)
#pragma unroll
            for (int q = 0; q < 4; ++q) {
                accT[m][q] = __builtin_amdgcn_mfma_f32_16x16x32_f16(aF[m], bT[q],
                                                                    accT[m][q], 0, 0, 0);
                if (!CLS)
                    accP[m][q] = __builtin_amdgcn_mfma_f32_16x16x32_f16(aF[m], bP[q],
                                                                        accP[m][q], 0, 0, 0);
            }
    }

#pragma unroll
    for (int m = 0; m < 2; ++m)
#pragma unroll
        for (int q = 0; q < 4; ++q) {
            int c = wc * 64 + q * 16 + (l & 15);
            float b = bias2[c];
#pragma unroll
            for (int reg = 0; reg < 4; ++reg) {
                int r = row0 + wr * 32 + m * 16 + lr4 + reg;
                if (r >= n) continue;
                if (CLS) {
                    Fo[(size_t)r * 128 + c] = accT[m][q][reg] + b;
                } else {
                    To[(size_t)r * 128 + c] = (f16)(accT[m][q][reg] + b);
                    Po[(size_t)r * 128 + c] = (f16)accP[m][q][reg];
                }
            }
        }
}

// ---------------------------------------------------------------------------
extern "C" void kernel_launch(void* const* d_in, const int* in_sizes, int n_in,
                              void* d_out, int out_size, void* d_ws, size_t ws_size,
                              hipStream_t stream) {
    const float* x    = (const float*)d_in[0];
    const int*   row  = (const int*)d_in[1];
    const int*   col  = (const int*)d_in[2];
    const float* W_sc = (const float*)d_in[3];
    const float* W_ci = (const float*)d_in[4];
    const float* b_ci = (const float*)d_in[5];
    const float* W_co = (const float*)d_in[6];
    const float* b_co = (const float*)d_in[7];
    const float* W0   = (const float*)d_in[8];
    const float* b0   = (const float*)d_in[9];
    const float* W1   = (const float*)d_in[10];
    const float* b1   = (const float*)d_in[11];
    const float* W2   = (const float*)d_in[12];
    const float* b2   = (const float*)d_in[13];
    const float* Wf   = (const float*)d_in[14];
    const float* bf   = (const float*)d_in[15];
    float* out = (float*)d_out;

    char* p = (char*)d_ws;
    auto alloc = [&](size_t bytes) {
        char* q = p;
        p += (bytes + 255) & ~(size_t)255;
        return q;
    };
    int*   cnt   = (int*)alloc((size_t)NN * CPAD * 4);  // padded: 1 counter / 64B
    int*   rp    = (int*)alloc((NN + 1) * 4);
    int*   bsum  = (int*)alloc(256 * 4);
    float* invd  = (float*)alloc(NN * 4);
    int*   ci    = (int*)alloc(EE * 4);
    int*   epack = (int*)alloc(EE * 4);
    f16*   x_h   = (f16*)alloc((size_t)NN * 256 * 2);
    f16*   sc_h  = (f16*)alloc((size_t)NN * 128 * 2);
    f16*   T_h   = (f16*)alloc((size_t)NN * 128 * 2);
    f16*   P_h   = (f16*)alloc((size_t)NN * 128 * 2);
    f16*   t0_h  = (f16*)alloc((size_t)NN * 128 * 2);
    // transposed fp16 weights [128 x K]
    f16* W0t_t = (f16*)alloc(256 * 128 * 2);
    f16* W0b_t = (f16*)alloc(256 * 128 * 2);
    f16* Wsc_t = (f16*)alloc(256 * 128 * 2);
    f16* W1t_t = (f16*)alloc(128 * 128 * 2);
    f16* W1b_t = (f16*)alloc(128 * 128 * 2);
    f16* W2t_t = (f16*)alloc(128 * 128 * 2);
    f16* W2b_t = (f16*)alloc(128 * 128 * 2);
    f16* Wci_t = (f16*)alloc(128 * 128 * 2);
    f16* Wco_t = (f16*)alloc(128 * 128 * 2);
    f16* Wf_t  = (f16*)alloc(128 * 128 * 2);

    const int NB_N  = (NN + 255) / 256;   // 196
    const int NB_E  = (EE + 255) / 256;   // 6250
    const int GB    = (NN + 63) / 64;     // 782 row-blocks (BM=64)
    const int AGG_B = (NN + 15) / 16;     // 3125 blocks (16 nodes/block)

    // ---- prep: convert x, zero counters, convert+transpose weights ----
    const int N4   = NN * 256 / 4;               // 3,200,000 float4
    const int NZ4  = NN * CPAD / 4;              // 200,000 int4
    const int ZB0  = (N4 + 255) / 256;           // 12500
    const int WB0  = ZB0 + (NZ4 + 255) / 256;    // +782
    const int WBLK = 84;
    const int WTOT = 3 * 32768 + 7 * 16384;      // 212,992
    WPtrs wp;
    wp.s[0] = W0;             wp.d[0] = W0t_t;
    wp.s[1] = W0 + 256 * 128; wp.d[1] = W0b_t;
    wp.s[2] = W_sc;           wp.d[2] = Wsc_t;
    wp.s[3] = W1;             wp.d[3] = W1t_t;
    wp.s[4] = W1 + 128 * 128; wp.d[4] = W1b_t;
    wp.s[5] = W2;             wp.d[5] = W2t_t;
    wp.s[6] = W2 + 128 * 128; wp.d[6] = W2b_t;
    wp.s[7] = W_ci;           wp.d[7] = Wci_t;
    wp.s[8] = W_co;           wp.d[8] = Wco_t;
    wp.s[9] = Wf;             wp.d[9] = Wf_t;
    k_prep<<<WB0 + WBLK, 256, 0, stream>>>(x, x_h, N4, cnt, NZ4, wp, WTOT,
                                           ZB0, WB0, WBLK);

    // ---- graph structure ----
    k_slot<<<NB_E, 256, 0, stream>>>(row, cnt, epack, EE);
    k_scan1<<<NB_N, 256, 0, stream>>>(cnt, bsum, NN);
    k_scan3<<<NB_N, 256, 0, stream>>>(cnt, bsum, rp, invd, NN, NB_N);
    k_fill<<<dim3(NB_E, NPASS), 256, 0, stream>>>(epack, col, rp, ci, EE);

    // ---- layer 0:  T = x@W0top + b0, P = x@W0bot, sc = x@W_sc ----
    k_mgemm<256, 3, false><<<dim3(GB, 3), 256, 0, stream>>>(
        x_h, W0t_t, W0b_t, Wsc_t, b0, T_h, P_h, sc_h, NN);
    k_agg2h<<<AGG_B, 256, 0, stream>>>(P_h, rp, ci, invd, T_h, t0_h, NN);    // o1

    // ---- gsc0 + layer1 projections fused ----
    k_fused<1, false><<<GB, 256, 0, stream>>>(
        sc_h, t0_h, Wci_t, Wco_t, W1t_t, W1b_t, b_ci, b_co, b1,
        T_h, P_h, nullptr, NN);
    k_agg2h<<<AGG_B, 256, 0, stream>>>(P_h, rp, ci, invd, T_h, t0_h, NN);    // o4

    // ---- gsc1 + layer2 projections fused ----
    k_fused<1, false><<<GB, 256, 0, stream>>>(
        sc_h, t0_h, Wci_t, Wco_t, W2t_t, W2b_t, b_ci, b_co, b2,
        T_h, P_h, nullptr, NN);
    k_agg2h<<<AGG_B, 256, 0, stream>>>(P_h, rp, ci, invd, T_h, t0_h, NN);    // o7

    // ---- gsc2 (no relu) + classifier fused (fp32 out) ----
    k_fused<0, true><<<GB, 256, 0, stream>>>(
        sc_h, t0_h, Wci_t, Wco_t, Wf_t, nullptr, b_ci, b_co, bf,
        nullptr, nullptr, out, NN);
}

// Round 12
// 512.316 us; speedup vs baseline: 1.1049x; 1.0631x over previous
//
#include <hip/hip_runtime.h>
#include <hip/hip_bf16.h>
#include <hip/hip_fp16.h>
#include <math.h>

// Problem constants (from reference)
#define NN 50000
#define EE 1600000
#define NFEAT 256
#define NHID 128
#define RNG 12500  // NN/4 — fill pass range (ci window 1.6MB < 4MB L2/XCD)
#define NPASS 4
#define CPAD 16    // counter padding: one counter per 64B line
#define GB 782     // (NN+63)/64 row-blocks
#define NGEMM (GB * 3)
#define NB_E 6250  // (EE+255)/256

typedef _Float16 f16;
typedef _Float16 f16x8 __attribute__((ext_vector_type(8)));
typedef _Float16 f16x4 __attribute__((ext_vector_type(4)));
typedef float f32x4 __attribute__((ext_vector_type(4)));

// ---------------------------------------------------------------------------
// Combined prep: fp32->fp16 convert of x, zero padded counters, convert+
// transpose all weights.
struct WPtrs {
    const float* s[10];
    f16* d[10];
};

__global__ __launch_bounds__(256) void k_prep(const float* __restrict__ x,
                                              f16* __restrict__ xh, int n4,
                                              int* __restrict__ cnt, int nz4,
                                              WPtrs wp, int wtotal,
                                              int zb0, int wb0, int wblocks) {
    int b = blockIdx.x;
    if (b < zb0) {
        int i = b * 256 + threadIdx.x;
        if (i < n4) {
            float4 v = reinterpret_cast<const float4*>(x)[i];
            f16x4 h = {(f16)v.x, (f16)v.y, (f16)v.z, (f16)v.w};
            reinterpret_cast<f16x4*>(xh)[i] = h;
        }
    } else if (b < wb0) {
        int i = (b - zb0) * 256 + threadIdx.x;
        if (i < nz4) reinterpret_cast<int4*>(cnt)[i] = make_int4(0, 0, 0, 0);
    } else {
        for (int idx = (b - wb0) * 256 + threadIdx.x; idx < wtotal;
             idx += wblocks * 256) {
            int wsel, rem, K;
            if (idx < 3 * 32768) { wsel = idx >> 15; rem = idx & 32767; K = 256; }
            else { int t = idx - 3 * 32768; wsel = 3 + (t >> 14); rem = t & 16383; K = 128; }
            int k = rem >> 7, c = rem & 127;
            wp.d[wsel][c * K + k] = (f16)wp.s[wsel][rem];
        }
    }
}

// ---------------------------------------------------------------------------
// MFMA GEMM pieces (BM=64, BN=128, BK=32; 4 waves 2x2; wave tile 32x64).
#define LDSSTR 40

__device__ __forceinline__ void stage_A(const f16* __restrict__ A, f16* sA,
                                        int row0, int K, int kb, int tid, int n) {
    int r = tid >> 2, ch = tid & 3;
    int gr = row0 + r;
    uint4 v = make_uint4(0, 0, 0, 0);
    if (gr < n) v = *reinterpret_cast<const uint4*>(A + (size_t)gr * K + kb + ch * 8);
    *reinterpret_cast<uint4*>(sA + r * LDSSTR + ch * 8) = v;
}

__device__ __forceinline__ void stage_B(const f16* __restrict__ Wt, f16* sB,
                                        int K, int kb, int tid) {
#pragma unroll
    for (int i = 0; i < 2; ++i) {
        int idx = tid + i * 256;
        int c = idx >> 2, ch = idx & 3;
        uint4 v = *reinterpret_cast<const uint4*>(Wt + (size_t)c * K + kb + ch * 8);
        *reinterpret_cast<uint4*>(sB + c * LDSSTR + ch * 8) = v;
    }
}

__device__ void gemm0_body(int bx, int by, f16* sA, f16* sB,
                           const f16* __restrict__ A,
                           const f16* __restrict__ Wt0,
                           const f16* __restrict__ Wt1,
                           const f16* __restrict__ Wt2,
                           const float* __restrict__ bias0,
                           f16* __restrict__ C0, f16* __restrict__ C1,
                           f16* __restrict__ C2, int n) {
    constexpr int K = 256;
    const f16* Wt = Wt0;
    const float* bias = bias0;
    f16* C = C0;
    if (by == 1) { Wt = Wt1; bias = nullptr; C = C1; }
    if (by == 2) { Wt = Wt2; bias = nullptr; C = C2; }

    const int tid = threadIdx.x;
    const int row0 = bx * 64;
    const int wid = tid >> 6, l = tid & 63;
    const int wr = wid >> 1, wc = wid & 1;
    const int lr = l & 15, lk = (l >> 4) * 8;

    f32x4 acc[2][4];
#pragma unroll
    for (int m = 0; m < 2; ++m)
#pragma unroll
        for (int q = 0; q < 4; ++q) acc[m][q] = (f32x4){0.f, 0.f, 0.f, 0.f};

    for (int kt = 0; kt < K / 32; ++kt) {
        stage_A(A, sA, row0, K, kt * 32, tid, n);
        stage_B(Wt, sB, K, kt * 32, tid);
        __syncthreads();
        f16x8 aF[2], bF[4];
#pragma unroll
        for (int m = 0; m < 2; ++m)
            aF[m] = *reinterpret_cast<f16x8*>(sA + (wr * 32 + m * 16 + lr) * LDSSTR + lk);
#pragma unroll
        for (int q = 0; q < 4; ++q)
            bF[q] = *reinterpret_cast<f16x8*>(sB + (wc * 64 + q * 16 + lr) * LDSSTR + lk);
#pragma unroll
        for (int m = 0; m < 2; ++m)
#pragma unroll
            for (int q = 0; q < 4; ++q)
                acc[m][q] = __builtin_amdgcn_mfma_f32_16x16x32_f16(aF[m], bF[q],
                                                                   acc[m][q], 0, 0, 0);
        __syncthreads();
    }

    const int lr4 = (l >> 4) * 4;
#pragma unroll
    for (int m = 0; m < 2; ++m)
#pragma unroll
        for (int q = 0; q < 4; ++q) {
            int c = wc * 64 + q * 16 + (l & 15);
            float b = bias ? bias[c] : 0.0f;
#pragma unroll
            for (int reg = 0; reg < 4; ++reg) {
                int r = row0 + wr * 32 + m * 16 + lr4 + reg;
                if (r >= n) continue;
                C[(size_t)r * 128 + c] = (f16)(acc[m][q][reg] + b);
            }
        }
}

// ---------------------------------------------------------------------------
// MERGED slot + layer-0 GEMM. Independent work co-scheduled in one dispatch:
// slot waves stall on atomic returns (VALUBusy ~0.6%), gemm waves keep the
// MFMA pipe busy on the same CUs. Period-11 interleave: 8 slot : 3 gemm.
__global__ __launch_bounds__(256) void k_slotgemm(
    const int* __restrict__ row, int* __restrict__ cnt,
    int* __restrict__ epack, int e,
    const f16* __restrict__ A,
    const f16* __restrict__ Wt0, const f16* __restrict__ Wt1,
    const f16* __restrict__ Wt2, const float* __restrict__ bias0,
    f16* __restrict__ C0, f16* __restrict__ C1, f16* __restrict__ C2, int n) {
    __shared__ f16 sA[64 * LDSSTR];
    __shared__ f16 sB[128 * LDSSTR];

    int p = blockIdx.x / 11, k = blockIdx.x % 11;
    bool isG = (k == 2) || (k == 6) || (k == 9);
    if (isG) {
        int idx = (k == 2) ? 0 : ((k == 6) ? 1 : 2);
        int g = p * 3 + idx;
        if (g >= NGEMM) return;
        gemm0_body(g % GB, g / GB, sA, sB, A, Wt0, Wt1, Wt2, bias0, C0, C1, C2, n);
    } else {
        int rank = k - (k > 2) - (k > 6) - (k > 9);
        int s = p * 8 + rank;
        if (s >= NB_E) return;
        int i = s * 256 + threadIdx.x;
        if (i < e) {
            int r = row[i];
            int sl = atomicAdd(&cnt[(size_t)r * CPAD], 1);
            epack[i] = (sl << 16) | r;
        }
    }
}

// ---------------------------------------------------------------------------
// scan step 1: per-block (256-elem) sums of padded counters
__global__ void k_scan1(const int* __restrict__ cnt, int* __restrict__ bsum, int n) {
    __shared__ int s[256];
    int t = threadIdx.x;
    int i = blockIdx.x * 256 + t;
    s[t] = (i < n) ? cnt[(size_t)i * CPAD] : 0;
    __syncthreads();
    for (int off = 128; off > 0; off >>= 1) {
        if (t < off) s[t] += s[t + off];
        __syncthreads();
    }
    if (t == 0) bsum[blockIdx.x] = s[0];
}

// scan step 2+3 fused
__global__ void k_scan3(const int* __restrict__ cnt, const int* __restrict__ bsum,
                        int* __restrict__ rp, float* __restrict__ invd,
                        int n, int nb) {
    __shared__ int buf[2][256];
    __shared__ int bpre[2][256];
    int t = threadIdx.x;

    bpre[0][t] = (t < nb) ? bsum[t] : 0;
    __syncthreads();
    int bs = 0;
    for (int off = 1; off < 256; off <<= 1) {
        int v = bpre[bs][t];
        if (t >= off) v += bpre[bs][t - off];
        bpre[bs ^ 1][t] = v;
        bs ^= 1;
        __syncthreads();
    }
    int base = (blockIdx.x == 0) ? 0 : bpre[bs][blockIdx.x - 1];

    int i = blockIdx.x * 256 + t;
    int v = (i < n) ? cnt[(size_t)i * CPAD] : 0;
    buf[0][t] = v;
    __syncthreads();
    int sel = 0;
    for (int off = 1; off < 256; off <<= 1) {
        int x = buf[sel][t];
        if (t >= off) x += buf[sel][t - off];
        buf[sel ^ 1][t] = x;
        sel ^= 1;
        __syncthreads();
    }
    int incl = buf[sel][t];
    int excl = incl - v;
    if (i < n) {
        rp[i] = base + excl;
        invd[i] = 1.0f / fmaxf((float)v, 1.0f);
        if (i == n - 1) rp[n] = base + incl;  // == E
    }
}

// range-partitioned fill, no atomics (live ci window L2-resident).
__global__ void k_fill(const int* __restrict__ epack, const int* __restrict__ col,
                       const int* __restrict__ rp, int* __restrict__ ci, int e) {
    int i = blockIdx.x * 256 + threadIdx.x;
    if (i >= e) return;
    int pk = epack[i];
    int r = pk & 0xFFFF;
    int lo = blockIdx.y * RNG;
    if (r >= lo && r < lo + RNG) ci[rp[r] + (pk >> 16)] = col[i];
}

// ---------------------------------------------------------------------------
// Fused SAGE aggregation, 16-deep shfl-broadcast gather:
// lane i loads ci[j+i] once; __shfl(.,u,16) broadcasts; 16 row-gathers in
// flight per 16-lane group. Tail = one clamped batch, predicated accumulate.
__global__ __launch_bounds__(256) void k_agg2h(const f16* __restrict__ P,
                                               const int* __restrict__ rp,
                                               const int* __restrict__ ci,
                                               const float* __restrict__ invd,
                                               const f16* __restrict__ T,
                                               f16* __restrict__ OUT, int n) {
    int node = blockIdx.x * 16 + (threadIdx.x >> 4);
    if (node >= n) return;
    int lane = threadIdx.x & 15;
    int s = rp[node], e = rp[node + 1];
    float acc[8];
#pragma unroll
    for (int q = 0; q < 8; ++q) acc[q] = 0.0f;

    int j = s;
    for (; j + 16 <= e; j += 16) {
        int civ = ci[j + lane];
        f16x8 v[16];
#pragma unroll
        for (int u = 0; u < 16; ++u) {
            int nb = __shfl(civ, u, 16);
            v[u] = *reinterpret_cast<const f16x8*>(P + (size_t)nb * 128 + lane * 8);
        }
#pragma unroll
        for (int u = 0; u < 16; ++u)
#pragma unroll
            for (int q = 0; q < 8; ++q) acc[q] += (float)v[u][q];
    }
    int rem = e - j;
    if (rem > 0) {
        int civ = ci[j + (lane < rem ? lane : rem - 1)];
        f16x8 v[16];
#pragma unroll
        for (int u = 0; u < 16; ++u) {
            int nb = __shfl(civ, u, 16);
            v[u] = *reinterpret_cast<const f16x8*>(P + (size_t)nb * 128 + lane * 8);
        }
#pragma unroll
        for (int u = 0; u < 16; ++u)
            if (u < rem)
#pragma unroll
                for (int q = 0; q < 8; ++q) acc[q] += (float)v[u][q];
    }

    float scl = invd[node];
    f16x8 tv = *reinterpret_cast<const f16x8*>(T + (size_t)node * 128 + lane * 8);
    f16x8 o;
#pragma unroll
    for (int q = 0; q < 8; ++q) o[q] = (f16)((float)tv[q] + scl * acc[q]);
    *reinterpret_cast<f16x8*>(OUT + (size_t)node * 128 + lane * 8) = o;
}

// ---------------------------------------------------------------------------
// Fused gated-skip + next-layer projections (unchanged from last round).
#define FSTR 136

template <int RELU, bool CLS>
__global__ __launch_bounds__(256) void k_fused(const f16* __restrict__ Asc,
                                               const f16* __restrict__ At0,
                                               const f16* __restrict__ Wci,
                                               const f16* __restrict__ Wco,
                                               const f16* __restrict__ WtT,
                                               const f16* __restrict__ WtP,
                                               const float* __restrict__ bci,
                                               const float* __restrict__ bco,
                                               const float* __restrict__ bias2,
                                               f16* __restrict__ To,
                                               f16* __restrict__ Po,
                                               float* __restrict__ Fo, int n) {
    __shared__ f16 lsc[64 * FSTR];
    __shared__ f16 lt0[64 * FSTR];
    __shared__ f16 lt1[64 * FSTR];

    const int tid = threadIdx.x;
    const int row0 = blockIdx.x * 64;
    const int wid = tid >> 6, l = tid & 63;
    const int wr = wid >> 1, wc = wid & 1;
    const int lr = l & 15, lk = (l >> 4) * 8;
    const int lr4 = (l >> 4) * 4;

#pragma unroll
    for (int i = 0; i < 4; ++i) {
        int idx = tid + i * 256;
        int r = idx >> 4, ch = idx & 15;
        int gr = row0 + r;
        uint4 vs = make_uint4(0, 0, 0, 0), vt = make_uint4(0, 0, 0, 0);
        if (gr < n) {
            vs = *reinterpret_cast<const uint4*>(Asc + (size_t)gr * 128 + ch * 8);
            vt = *reinterpret_cast<const uint4*>(At0 + (size_t)gr * 128 + ch * 8);
        }
        *reinterpret_cast<uint4*>(lsc + r * FSTR + ch * 8) = vs;
        *reinterpret_cast<uint4*>(lt0 + r * FSTR + ch * 8) = vt;
    }
    __syncthreads();

    f32x4 accG[2][4];
#pragma unroll
    for (int m = 0; m < 2; ++m)
#pragma unroll
        for (int q = 0; q < 4; ++q) accG[m][q] = (f32x4){0.f, 0.f, 0.f, 0.f};

#pragma unroll
    for (int kt = 0; kt < 4; ++kt) {
        f16x8 aS[2], aT[2], bC[4], bO[4];
#pragma unroll
        for (int m = 0; m < 2; ++m) {
            int rr = (wr * 32 + m * 16 + lr) * FSTR + kt * 32 + lk;
            aS[m] = *reinterpret_cast<const f16x8*>(lsc + rr);
            aT[m] = *reinterpret_cast<const f16x8*>(lt0 + rr);
        }
#pragma unroll
        for (int q = 0; q < 4; ++q) {
            int c = wc * 64 + q * 16 + lr;
            bC[q] = *reinterpret_cast<const f16x8*>(Wci + (size_t)c * 128 + kt * 32 + lk);
            bO[q] = *reinterpret_cast<const f16x8*>(Wco + (size_t)c * 128 + kt * 32 + lk);
        }
#pragma unroll
        for (int m = 0; m < 2; ++m)
#pragma unroll
            for (int q = 0; q < 4; ++q) {
                accG[m][q] = __builtin_amdgcn_mfma_f32_16x16x32_f16(aS[m], bC[q],
                                                                    accG[m][q], 0, 0, 0);
                accG[m][q] = __builtin_amdgcn_mfma_f32_16x16x32_f16(aT[m], bO[q],
                                                                    accG[m][q], 0, 0, 0);
            }
    }

#pragma unroll
    for (int m = 0; m < 2; ++m)
#pragma unroll
        for (int q = 0; q < 4; ++q) {
            int c = wc * 64 + q * 16 + (l & 15);
            float bb = bci[c] + bco[c];
#pragma unroll
            for (int reg = 0; reg < 4; ++reg) {
                int lrow = wr * 32 + m * 16 + lr4 + reg;
                float v = accG[m][q][reg] + bb;
                float z = 1.0f / (1.0f + __expf(-v));
                float o = (float)lt0[lrow * FSTR + c];
                float s = (float)lsc[lrow * FSTR + c];
                float t1v = z * o + (1.0f - z) * s;
                if (RELU) t1v = fmaxf(t1v, 0.0f);
                lt1[lrow * FSTR + c] = (f16)t1v;
            }
        }
    __syncthreads();

    f32x4 accT[2][4], accP[2][4];
#pragma unroll
    for (int m = 0; m < 2; ++m)
#pragma unroll
        for (int q = 0; q < 4; ++q) {
            accT[m][q] = (f32x4){0.f, 0.f, 0.f, 0.f};
            accP[m][q] = (f32x4){0.f, 0.f, 0.f, 0.f};
        }

#pragma unroll
    for (int kt = 0; kt < 4; ++kt) {
        f16x8 aF[2], bT[4], bP[4];
#pragma unroll
        for (int m = 0; m < 2; ++m)
            aF[m] = *reinterpret_cast<const f16x8*>(
                lt1 + (wr * 32 + m * 16 + lr) * FSTR + kt * 32 + lk);
#pragma unroll
        for (int q = 0; q < 4; ++q) {
            int c = wc * 64 + q * 16 + lr;
            bT[q] = *reinterpret_cast<const f16x8*>(WtT + (size_t)c * 128 + kt * 32 + lk);
            if (!CLS)
                bP[q] = *reinterpret_cast<const f16x8*>(WtP + (size_t)c * 128 + kt * 32 + lk);
        }
#pragma unroll
        for (int m = 0; m < 2; ++m)
#pragma unroll
            for (int q = 0; q < 4; ++q) {
                accT[m][q] = __builtin_amdgcn_mfma_f32_16x16x32_f16(aF[m], bT[q],
                                                                    accT[m][q], 0, 0, 0);
                if (!CLS)
                    accP[m][q] = __builtin_amdgcn_mfma_f32_16x16x32_f16(aF[m], bP[q],
                                                                        accP[m][q], 0, 0, 0);
            }
    }

#pragma unroll
    for (int m = 0; m < 2; ++m)
#pragma unroll
        for (int q = 0; q < 4; ++q) {
            int c = wc * 64 + q * 16 + (l & 15);
            float b = bias2[c];
#pragma unroll
            for (int reg = 0; reg < 4; ++reg) {
                int r = row0 + wr * 32 + m * 16 + lr4 + reg;
                if (r >= n) continue;
                if (CLS) {
                    Fo[(size_t)r * 128 + c] = accT[m][q][reg] + b;
                } else {
                    To[(size_t)r * 128 + c] = (f16)(accT[m][q][reg] + b);
                    Po[(size_t)r * 128 + c] = (f16)accP[m][q][reg];
                }
            }
        }
}

// ---------------------------------------------------------------------------
extern "C" void kernel_launch(void* const* d_in, const int* in_sizes, int n_in,
                              void* d_out, int out_size, void* d_ws, size_t ws_size,
                              hipStream_t stream) {
    const float* x    = (const float*)d_in[0];
    const int*   row  = (const int*)d_in[1];
    const int*   col  = (const int*)d_in[2];
    const float* W_sc = (const float*)d_in[3];
    const float* W_ci = (const float*)d_in[4];
    const float* b_ci = (const float*)d_in[5];
    const float* W_co = (const float*)d_in[6];
    const float* b_co = (const float*)d_in[7];
    const float* W0   = (const float*)d_in[8];
    const float* b0   = (const float*)d_in[9];
    const float* W1   = (const float*)d_in[10];
    const float* b1   = (const float*)d_in[11];
    const float* W2   = (const float*)d_in[12];
    const float* b2   = (const float*)d_in[13];
    const float* Wf   = (const float*)d_in[14];
    const float* bf   = (const float*)d_in[15];
    float* out = (float*)d_out;

    char* p = (char*)d_ws;
    auto alloc = [&](size_t bytes) {
        char* q = p;
        p += (bytes + 255) & ~(size_t)255;
        return q;
    };
    int*   cnt   = (int*)alloc((size_t)NN * CPAD * 4);  // padded: 1 counter / 64B
    int*   rp    = (int*)alloc((NN + 1) * 4);
    int*   bsum  = (int*)alloc(256 * 4);
    float* invd  = (float*)alloc(NN * 4);
    int*   ci    = (int*)alloc(EE * 4);
    int*   epack = (int*)alloc(EE * 4);
    f16*   x_h   = (f16*)alloc((size_t)NN * 256 * 2);
    f16*   sc_h  = (f16*)alloc((size_t)NN * 128 * 2);
    f16*   T_h   = (f16*)alloc((size_t)NN * 128 * 2);
    f16*   P_h   = (f16*)alloc((size_t)NN * 128 * 2);
    f16*   t0_h  = (f16*)alloc((size_t)NN * 128 * 2);
    // transposed fp16 weights [128 x K]
    f16* W0t_t = (f16*)alloc(256 * 128 * 2);
    f16* W0b_t = (f16*)alloc(256 * 128 * 2);
    f16* Wsc_t = (f16*)alloc(256 * 128 * 2);
    f16* W1t_t = (f16*)alloc(128 * 128 * 2);
    f16* W1b_t = (f16*)alloc(128 * 128 * 2);
    f16* W2t_t = (f16*)alloc(128 * 128 * 2);
    f16* W2b_t = (f16*)alloc(128 * 128 * 2);
    f16* Wci_t = (f16*)alloc(128 * 128 * 2);
    f16* Wco_t = (f16*)alloc(128 * 128 * 2);
    f16* Wf_t  = (f16*)alloc(128 * 128 * 2);

    const int NB_N  = (NN + 255) / 256;   // 196
    const int AGG_B = (NN + 15) / 16;     // 3125 blocks (16 nodes/block)
    const int MGRID = GB * 11;            // 8602: period-11 merged grid

    // ---- prep: convert x, zero counters, convert+transpose weights ----
    const int N4   = NN * 256 / 4;               // 3,200,000 float4
    const int NZ4  = NN * CPAD / 4;              // 200,000 int4
    const int ZB0  = (N4 + 255) / 256;           // 12500
    const int WB0  = ZB0 + (NZ4 + 255) / 256;    // +782
    const int WBLK = 84;
    const int WTOT = 3 * 32768 + 7 * 16384;      // 212,992
    WPtrs wp;
    wp.s[0] = W0;             wp.d[0] = W0t_t;
    wp.s[1] = W0 + 256 * 128; wp.d[1] = W0b_t;
    wp.s[2] = W_sc;           wp.d[2] = Wsc_t;
    wp.s[3] = W1;             wp.d[3] = W1t_t;
    wp.s[4] = W1 + 128 * 128; wp.d[4] = W1b_t;
    wp.s[5] = W2;             wp.d[5] = W2t_t;
    wp.s[6] = W2 + 128 * 128; wp.d[6] = W2b_t;
    wp.s[7] = W_ci;           wp.d[7] = Wci_t;
    wp.s[8] = W_co;           wp.d[8] = Wco_t;
    wp.s[9] = Wf;             wp.d[9] = Wf_t;
    k_prep<<<WB0 + WBLK, 256, 0, stream>>>(x, x_h, N4, cnt, NZ4, wp, WTOT,
                                           ZB0, WB0, WBLK);

    // ---- merged: slot atomics co-scheduled with layer-0 GEMM ----
    k_slotgemm<<<MGRID, 256, 0, stream>>>(row, cnt, epack, EE,
                                          x_h, W0t_t, W0b_t, Wsc_t, b0,
                                          T_h, P_h, sc_h, NN);

    // ---- graph structure ----
    k_scan1<<<NB_N, 256, 0, stream>>>(cnt, bsum, NN);
    k_scan3<<<NB_N, 256, 0, stream>>>(cnt, bsum, rp, invd, NN, NB_N);
    k_fill<<<dim3(NB_E, NPASS), 256, 0, stream>>>(epack, col, rp, ci, EE);

    // ---- layer 0 aggregation ----
    k_agg2h<<<AGG_B, 256, 0, stream>>>(P_h, rp, ci, invd, T_h, t0_h, NN);    // o1

    // ---- gsc0 + layer1 projections fused ----
    k_fused<1, false><<<GB, 256, 0, stream>>>(
        sc_h, t0_h, Wci_t, Wco_t, W1t_t, W1b_t, b_ci, b_co, b1,
        T_h, P_h, nullptr, NN);
    k_agg2h<<<AGG_B, 256, 0, stream>>>(P_h, rp, ci, invd, T_h, t0_h, NN);    // o4

    // ---- gsc1 + layer2 projections fused ----
    k_fused<1, false><<<GB, 256, 0, stream>>>(
        sc_h, t0_h, Wci_t, Wco_t, W2t_t, W2b_t, b_ci, b_co, b2,
        T_h, P_h, nullptr, NN);
    k_agg2h<<<AGG_B, 256, 0, stream>>>(P_h, rp, ci, invd, T_h, t0_h, NN);    // o7

    // ---- gsc2 (no relu) + classifier fused (fp32 out) ----
    k_fused<0, true><<<GB, 256, 0, stream>>>(
        sc_h, t0_h, Wci_t, Wco_t, Wf_t, nullptr, b_ci, b_co, bf,
        nullptr, nullptr, out, NN);
}